// Round 1
// baseline (1670.068 us; speedup 1.0000x reference)
//
#include <hip/hip_runtime.h>
#include <hip/hip_bf16.h>

// GCN: 3 layers. Per layer: h = H_in @ W; out[col] += norm_e * h[row]; out += dinv^2*h + b; relu(1,2)
// norm_e = dinv[row]*ew*dinv[col], deg[i] = sum_{col==i} ew + 1, dinv = rsqrt(deg)
// Strategy: build col-sorted CSR once (histogram+scan+scatter), then per layer:
//   fp32 tiled GEMM -> h (ws), gather-aggregate (no atomics) -> d_out (ping-pong as next input).

#define D 256            // hidden/out width (fixed by problem)
#define SCAN_CHUNK 2048

__global__ __launch_bounds__(256) void hist_kernel(const int* __restrict__ col,
                                                   const float* __restrict__ ew,
                                                   float* __restrict__ deg,
                                                   int* __restrict__ cnt, int E) {
    int e = blockIdx.x * 256 + threadIdx.x;
    if (e < E) {
        int c = col[e];
        atomicAdd(&deg[c], ew[e]);
        atomicAdd(&cnt[c], 1);
    }
}

__global__ __launch_bounds__(256) void dinv_kernel(float* __restrict__ deg, int N) {
    int i = blockIdx.x * 256 + threadIdx.x;
    if (i < N) deg[i] = rsqrtf(deg[i] + 1.0f);   // becomes dinv in-place; deg+1 >= 1 always
}

// exclusive scan of cnt[N] -> rowptr[N]; per-chunk totals -> bsum
__global__ __launch_bounds__(256) void scan1_kernel(const int* __restrict__ cnt,
                                                    int* __restrict__ rowptr,
                                                    int* __restrict__ bsum, int N) {
    __shared__ int sd[256];
    int b = blockIdx.x, t = threadIdx.x;
    int base = b * SCAN_CHUNK + t * 8;
    int v[8];
    int tsum = 0;
#pragma unroll
    for (int j = 0; j < 8; j++) {
        v[j] = (base + j < N) ? cnt[base + j] : 0;
        tsum += v[j];
    }
    sd[t] = tsum;
    __syncthreads();
#pragma unroll
    for (int off = 1; off < 256; off <<= 1) {
        int x = (t >= off) ? sd[t - off] : 0;
        __syncthreads();
        sd[t] += x;
        __syncthreads();
    }
    int excl = sd[t] - tsum;
    if (t == 255) bsum[b] = sd[255];
    int run = excl;
#pragma unroll
    for (int j = 0; j < 8; j++) {
        if (base + j < N) rowptr[base + j] = run;
        run += v[j];
    }
}

__global__ void scan2_kernel(int* __restrict__ bsum, int nb) {
    int lane = threadIdx.x; // 64 threads, 1 wave
    int running = 0;
    for (int base = 0; base < nb; base += 64) {
        int idx = base + lane;
        int v = (idx < nb) ? bsum[idx] : 0;
        int orig = v;
#pragma unroll
        for (int off = 1; off < 64; off <<= 1) {
            int x = __shfl_up(v, off);
            if (lane >= off) v += x;
        }
        if (idx < nb) bsum[idx] = v - orig + running;
        running += __shfl(v, 63);
    }
}

__global__ __launch_bounds__(256) void scan3_kernel(int* __restrict__ rowptr,
                                                    const int* __restrict__ bsum, int N) {
    int i = blockIdx.x * 256 + threadIdx.x;
    if (i < N) rowptr[i] += bsum[i / SCAN_CHUNK];
}

__global__ __launch_bounds__(256) void scatter_kernel(const int* __restrict__ row,
                                                      const int* __restrict__ col,
                                                      const float* __restrict__ ew,
                                                      const float* __restrict__ dinv,
                                                      const int* __restrict__ rowptr,
                                                      int* __restrict__ fill,
                                                      int* __restrict__ ssort,
                                                      float* __restrict__ wsort, int E) {
    int e = blockIdx.x * 256 + threadIdx.x;
    if (e < E) {
        int c = col[e], r = row[e];
        float nrm = dinv[r] * ew[e] * dinv[c];
        int pos = rowptr[c] + atomicAdd(&fill[c], 1);
        ssort[pos] = r;
        wsort[pos] = nrm;
    }
}

// C[N,256] = A[N,K] @ W[K,256]. Block (32,8)=256 thr, tile 64x128, micro 8x4.
template <int K>
__global__ __launch_bounds__(256) void gemm_kernel(const float* __restrict__ A,
                                                   const float* __restrict__ W,
                                                   float* __restrict__ C, int N) {
    constexpr int BM = 64, BN = 128, BK = 32;
    __shared__ float aT[BK][BM];   // transposed: aT[k][r]
    __shared__ float bS[BK][BN];
    const int tx = threadIdx.x;    // 0..31 -> cols
    const int ty = threadIdx.y;    // 0..7  -> rows
    const int tid = ty * 32 + tx;
    const int r0 = blockIdx.x * BM;
    const int c0 = blockIdx.y * BN;
    float acc[8][4] = {};

    for (int k0 = 0; k0 < K; k0 += BK) {
        // stage A: 64 rows x 32 k = 512 float4, 2 per thread (transposed into LDS)
#pragma unroll
        for (int i = 0; i < 2; i++) {
            int l = tid * 2 + i;     // 0..511
            int r = l >> 3;          // 0..63
            int q = l & 7;           // float4 index along k
            float4 av = make_float4(0.f, 0.f, 0.f, 0.f);
            int gr = r0 + r;
            if (gr < N) av = *reinterpret_cast<const float4*>(&A[(size_t)gr * K + k0 + 4 * q]);
            aT[4 * q + 0][r] = av.x;
            aT[4 * q + 1][r] = av.y;
            aT[4 * q + 2][r] = av.z;
            aT[4 * q + 3][r] = av.w;
        }
        // stage B: 32 k x 128 c = 1024 float4, 4 per thread
#pragma unroll
        for (int i = 0; i < 4; i++) {
            int l = i * 256 + tid;   // 0..1023
            int k = l >> 5;
            int c4 = l & 31;
            float4 bv = *reinterpret_cast<const float4*>(&W[(size_t)(k0 + k) * D + c0 + 4 * c4]);
            *reinterpret_cast<float4*>(&bS[k][4 * c4]) = bv;
        }
        __syncthreads();
#pragma unroll
        for (int k = 0; k < BK; k++) {
            float aF[8], bF[4];
            *reinterpret_cast<float4*>(&aF[0]) = *reinterpret_cast<const float4*>(&aT[k][ty * 8]);
            *reinterpret_cast<float4*>(&aF[4]) = *reinterpret_cast<const float4*>(&aT[k][ty * 8 + 4]);
            *reinterpret_cast<float4*>(&bF[0]) = *reinterpret_cast<const float4*>(&bS[k][tx * 4]);
#pragma unroll
            for (int i = 0; i < 8; i++)
#pragma unroll
                for (int j = 0; j < 4; j++)
                    acc[i][j] = fmaf(aF[i], bF[j], acc[i][j]);
        }
        __syncthreads();
    }
#pragma unroll
    for (int i = 0; i < 8; i++) {
        int gr = r0 + ty * 8 + i;
        if (gr < N) {
            float4 v = make_float4(acc[i][0], acc[i][1], acc[i][2], acc[i][3]);
            *reinterpret_cast<float4*>(&C[(size_t)gr * D + c0 + tx * 4]) = v;
        }
    }
}

// one 64-thread block per node; float4 per lane (one wave reads a full 1KB h-row per edge)
template <bool RELU>
__global__ __launch_bounds__(64) void agg_kernel(const float* __restrict__ h,
                                                 const float* __restrict__ dinv,
                                                 const float* __restrict__ bias,
                                                 const int* __restrict__ rowptr,
                                                 const int* __restrict__ ssort,
                                                 const float* __restrict__ wsort,
                                                 float* __restrict__ out, int N, int E) {
    int i = blockIdx.x;
    int t = threadIdx.x;           // 0..63
    const float4* h4 = reinterpret_cast<const float4*>(h);
    float di = dinv[i];
    float d2 = di * di;
    float4 hv = h4[(size_t)i * 64 + t];
    float4 acc;
    acc.x = d2 * hv.x; acc.y = d2 * hv.y; acc.z = d2 * hv.z; acc.w = d2 * hv.w;
    int s = rowptr[i];
    int e = (i == N - 1) ? E : rowptr[i + 1];
    for (int k = s; k < e; k++) {
        int src = ssort[k];
        float w = wsort[k];
        float4 v = h4[(size_t)src * 64 + t];
        acc.x = fmaf(w, v.x, acc.x);
        acc.y = fmaf(w, v.y, acc.y);
        acc.z = fmaf(w, v.z, acc.z);
        acc.w = fmaf(w, v.w, acc.w);
    }
    float4 bb = reinterpret_cast<const float4*>(bias)[t];
    acc.x += bb.x; acc.y += bb.y; acc.z += bb.z; acc.w += bb.w;
    if (RELU) {
        acc.x = fmaxf(acc.x, 0.f); acc.y = fmaxf(acc.y, 0.f);
        acc.z = fmaxf(acc.z, 0.f); acc.w = fmaxf(acc.w, 0.f);
    }
    reinterpret_cast<float4*>(out)[(size_t)i * 64 + t] = acc;
}

extern "C" void kernel_launch(void* const* d_in, const int* in_sizes, int n_in,
                              void* d_out, int out_size, void* d_ws, size_t ws_size,
                              hipStream_t stream) {
    const float* x  = (const float*)d_in[0];
    const int*   ei = (const int*)d_in[1];
    const float* ew = (const float*)d_in[2];
    const float* W1 = (const float*)d_in[3];
    const float* b1 = (const float*)d_in[4];
    const float* W2 = (const float*)d_in[5];
    const float* b2 = (const float*)d_in[6];
    const float* W3 = (const float*)d_in[7];
    const float* b3 = (const float*)d_in[8];
    const int N = in_sizes[0] / 512;
    const int E = in_sizes[2];
    const int* row = ei;
    const int* col = ei + E;
    float* out = (float*)d_out;

    char* ws = (char*)d_ws;
    size_t off = 0;
    auto alloc = [&](size_t bytes) -> void* {
        void* p = ws + off;
        off += (bytes + 255) / 256 * 256;
        return p;
    };
    float* h      = (float*)alloc((size_t)N * D * sizeof(float));   // 102.4 MB
    float* dinv   = (float*)alloc((size_t)N * sizeof(float));       // deg -> dinv in place
    int*   cnt    = (int*)alloc((size_t)N * sizeof(int));
    int*   fill   = (int*)alloc((size_t)N * sizeof(int));
    int*   rowptr = (int*)alloc((size_t)(N + 1) * sizeof(int));
    int*   bsum   = (int*)alloc(4096 * sizeof(int));
    int*   ssort  = (int*)alloc((size_t)E * sizeof(int));
    float* wsort  = (float*)alloc((size_t)E * sizeof(float));

    hipMemsetAsync(dinv, 0, (size_t)N * sizeof(float), stream);
    hipMemsetAsync(cnt, 0, (size_t)N * sizeof(int), stream);
    hipMemsetAsync(fill, 0, (size_t)N * sizeof(int), stream);

    int gE = (E + 255) / 256;
    int gN = (N + 255) / 256;
    hist_kernel<<<gE, 256, 0, stream>>>(col, ew, dinv, cnt, E);
    dinv_kernel<<<gN, 256, 0, stream>>>(dinv, N);
    int nb = (N + SCAN_CHUNK - 1) / SCAN_CHUNK;
    scan1_kernel<<<nb, 256, 0, stream>>>(cnt, rowptr, bsum, N);
    scan2_kernel<<<1, 64, 0, stream>>>(bsum, nb);
    scan3_kernel<<<gN, 256, 0, stream>>>(rowptr, bsum, N);
    scatter_kernel<<<gE, 256, 0, stream>>>(row, col, ew, dinv, rowptr, fill, ssort, wsort, E);

    dim3 gg((N + 63) / 64, 2), gb(32, 8);
    // layer 1: x[N,512] @ W1 -> h; aggregate -> out (relu)
    gemm_kernel<512><<<gg, gb, 0, stream>>>(x, W1, h, N);
    agg_kernel<true><<<N, 64, 0, stream>>>(h, dinv, b1, rowptr, ssort, wsort, out, N, E);
    // layer 2: out @ W2 -> h; aggregate -> out (relu)
    gemm_kernel<256><<<gg, gb, 0, stream>>>(out, W2, h, N);
    agg_kernel<true><<<N, 64, 0, stream>>>(h, dinv, b2, rowptr, ssort, wsort, out, N, E);
    // layer 3: out @ W3 -> h; aggregate -> out (no relu)
    gemm_kernel<256><<<gg, gb, 0, stream>>>(out, W3, h, N);
    agg_kernel<false><<<N, 64, 0, stream>>>(h, dinv, b3, rowptr, ssort, wsort, out, N, E);
}

// Round 2
// 824.297 us; speedup vs baseline: 2.0261x; 2.0261x over previous
//
#include <hip/hip_runtime.h>
#include <hip/hip_bf16.h>

// GCN 3-layer. Round 2: bf16 MFMA GEMM (m97-style 128x128 tile, BK=64, swizzled LDS,
// global_load_lds) + bf16 h for the gather-aggregation (halves gather bytes).
// CSR build (col-sorted) unchanged from round 1.

#define D 256
#define SCAN_CHUNK 2048

typedef unsigned short ushort_t;
typedef float f32x4 __attribute__((ext_vector_type(4)));
typedef short bf16x8 __attribute__((ext_vector_type(8)));

__device__ __forceinline__ float u2f(ushort_t u) {
    return __uint_as_float(((unsigned)u) << 16);
}
__device__ __forceinline__ ushort_t f2b(float f) {   // round-to-nearest-even
    unsigned u = __float_as_uint(f);
    return (ushort_t)((u + 0x7FFFu + ((u >> 16) & 1u)) >> 16);
}
__device__ __forceinline__ void gload_lds16(const ushort_t* g, ushort_t* l) {
    __builtin_amdgcn_global_load_lds((const __attribute__((address_space(1))) unsigned int*)g,
                                     (__attribute__((address_space(3))) unsigned int*)l, 16, 0, 0);
}

// ---------------- CSR build ----------------
__global__ __launch_bounds__(256) void hist_kernel(const int* __restrict__ col,
                                                   const float* __restrict__ ew,
                                                   float* __restrict__ deg,
                                                   int* __restrict__ cnt, int E) {
    int e = blockIdx.x * 256 + threadIdx.x;
    if (e < E) {
        int c = col[e];
        atomicAdd(&deg[c], ew[e]);
        atomicAdd(&cnt[c], 1);
    }
}

__global__ __launch_bounds__(256) void dinv_kernel(float* __restrict__ deg, int N) {
    int i = blockIdx.x * 256 + threadIdx.x;
    if (i < N) deg[i] = rsqrtf(deg[i] + 1.0f);
}

__global__ __launch_bounds__(256) void scan1_kernel(const int* __restrict__ cnt,
                                                    int* __restrict__ rowptr,
                                                    int* __restrict__ bsum, int N) {
    __shared__ int sd[256];
    int b = blockIdx.x, t = threadIdx.x;
    int base = b * SCAN_CHUNK + t * 8;
    int v[8];
    int tsum = 0;
#pragma unroll
    for (int j = 0; j < 8; j++) {
        v[j] = (base + j < N) ? cnt[base + j] : 0;
        tsum += v[j];
    }
    sd[t] = tsum;
    __syncthreads();
#pragma unroll
    for (int off = 1; off < 256; off <<= 1) {
        int x = (t >= off) ? sd[t - off] : 0;
        __syncthreads();
        sd[t] += x;
        __syncthreads();
    }
    int excl = sd[t] - tsum;
    if (t == 255) bsum[b] = sd[255];
    int run = excl;
#pragma unroll
    for (int j = 0; j < 8; j++) {
        if (base + j < N) rowptr[base + j] = run;
        run += v[j];
    }
}

__global__ void scan2_kernel(int* __restrict__ bsum, int nb) {
    int lane = threadIdx.x;
    int running = 0;
    for (int base = 0; base < nb; base += 64) {
        int idx = base + lane;
        int v = (idx < nb) ? bsum[idx] : 0;
        int orig = v;
#pragma unroll
        for (int off = 1; off < 64; off <<= 1) {
            int x = __shfl_up(v, off);
            if (lane >= off) v += x;
        }
        if (idx < nb) bsum[idx] = v - orig + running;
        running += __shfl(v, 63);
    }
}

__global__ __launch_bounds__(256) void scan3_kernel(int* __restrict__ rowptr,
                                                    const int* __restrict__ bsum, int N) {
    int i = blockIdx.x * 256 + threadIdx.x;
    if (i < N) rowptr[i] += bsum[i / SCAN_CHUNK];
}

__global__ __launch_bounds__(256) void scatter_kernel(const int* __restrict__ row,
                                                      const int* __restrict__ col,
                                                      const float* __restrict__ ew,
                                                      const float* __restrict__ dinv,
                                                      const int* __restrict__ rowptr,
                                                      int* __restrict__ fill,
                                                      int* __restrict__ ssort,
                                                      float* __restrict__ wsort, int E) {
    int e = blockIdx.x * 256 + threadIdx.x;
    if (e < E) {
        int c = col[e], r = row[e];
        float nrm = dinv[r] * ew[e] * dinv[c];
        int pos = rowptr[c] + atomicAdd(&fill[c], 1);
        ssort[pos] = r;
        wsort[pos] = nrm;
    }
}

// W[K][C] fp32 -> WT[C][K] bf16 (pre-transposed so B-tiles stage via global_load_lds)
__global__ __launch_bounds__(256) void cvtT_kernel(const float* __restrict__ W,
                                                   ushort_t* __restrict__ WT, int K, int C) {
    int i = blockIdx.x * 256 + threadIdx.x;
    if (i < K * C) {
        int c = i / K, k = i - c * K;
        WT[i] = f2b(W[(size_t)k * C + c]);
    }
}

// ---------------- MFMA GEMM ----------------
// C[Npad,256](bf16) = A[Npad,K] @ WT^T. 256 thr = 4 waves (2x2), tile 128x128, BK=64.
// LDS tiles As/Bs: [128][64] bf16, 8x16B slots/row, slot XOR-swizzled by (row&7).
template <int K, bool AF32>
__global__ __launch_bounds__(256) void gemm_mfma(const void* __restrict__ Ap,
                                                 const ushort_t* __restrict__ WT,
                                                 ushort_t* __restrict__ C, int nvalid) {
    __shared__ ushort_t As[128 * 64];
    __shared__ ushort_t Bs[128 * 64];
    const int tid = threadIdx.x;
    const int lane = tid & 63, wave = tid >> 6;
    const int wrow = wave >> 1, wcol = wave & 1;
    const int fr = lane & 15, fq = lane >> 4;
    const int c0 = blockIdx.x * 128;   // grid.x = 2 (cols) so row-tile pairs are adjacent in dispatch
    const int r0 = blockIdx.y * 128;

    f32x4 acc[4][4] = {};

    for (int k0 = 0; k0 < K; k0 += 64) {
        // ---- stage A-tile [128][64] ----
        if constexpr (AF32) {
            const float* Af = (const float*)Ap;
#pragma unroll
            for (int i = 0; i < 8; ++i) {
                int idx = i * 256 + tid;          // 0..2047 float4s
                int rowt = idx >> 4;              // 0..127
                int c4 = idx & 15;                // float4 within row (4 elems)
                int grow = r0 + rowt;
                if (grow >= nvalid) grow = nvalid - 1;   // stay in-bounds; pad rows unused
                float4 v = *(const float4*)&Af[(size_t)grow * K + k0 + c4 * 4];
                ushort4 h;
                h.x = f2b(v.x); h.y = f2b(v.y); h.z = f2b(v.z); h.w = f2b(v.w);
                int slot = c4 >> 1, half = c4 & 1;
                int off = rowt * 64 + ((slot ^ (rowt & 7)) << 3) + (half << 2);
                *(ushort4*)&As[off] = h;
            }
        } else {
            const ushort_t* Ab = (const ushort_t*)Ap;
#pragma unroll
            for (int q = 0; q < 4; ++q) {
                int qa = wave * 4 + q;            // 0..15, 8 rows each
                int rowt = qa * 8 + (lane >> 3);
                int g = (lane & 7) ^ (lane >> 3); // pre-swizzled global slot
                gload_lds16(&Ab[(size_t)(r0 + rowt) * K + k0 + g * 8], &As[qa * 512]);
            }
        }
        // ---- stage B-tile: Bs[col][k] from WT[c0+col][k] ----
#pragma unroll
        for (int q = 0; q < 4; ++q) {
            int qb = wave * 4 + q;
            int rowt = qb * 8 + (lane >> 3);
            int g = (lane & 7) ^ (lane >> 3);
            gload_lds16(&WT[(size_t)(c0 + rowt) * K + k0 + g * 8], &Bs[qb * 512]);
        }
        __syncthreads();

        // ---- fragments + MFMA ----
        bf16x8 aF[2][4], bF[2][4];
#pragma unroll
        for (int kk = 0; kk < 2; ++kk) {
            int g = (kk * 4 + fq) ^ (fr & 7);     // swizzled slot (row%8 == fr%8)
#pragma unroll
            for (int m = 0; m < 4; ++m) {
                int arow = wrow * 64 + m * 16 + fr;
                aF[kk][m] = *(const bf16x8*)&As[arow * 64 + g * 8];
            }
#pragma unroll
            for (int n = 0; n < 4; ++n) {
                int bcol = wcol * 64 + n * 16 + fr;
                bF[kk][n] = *(const bf16x8*)&Bs[bcol * 64 + g * 8];
            }
        }
#pragma unroll
        for (int kk = 0; kk < 2; ++kk)
#pragma unroll
            for (int m = 0; m < 4; ++m)
#pragma unroll
                for (int n = 0; n < 4; ++n)
                    acc[m][n] = __builtin_amdgcn_mfma_f32_16x16x32_bf16(
                        aF[kk][m], bF[kk][n], acc[m][n], 0, 0, 0);
        __syncthreads();
    }

    // ---- epilogue: D[i][j]: j = lane&15, i = (lane>>4)*4 + r ----
#pragma unroll
    for (int m = 0; m < 4; ++m) {
        int gr0 = r0 + wrow * 64 + m * 16 + fq * 4;
#pragma unroll
        for (int n = 0; n < 4; ++n) {
            int gc = c0 + wcol * 64 + n * 16 + fr;
#pragma unroll
            for (int r = 0; r < 4; ++r) {
                int gr = gr0 + r;
                if (gr < nvalid) C[(size_t)gr * D + gc] = f2b(acc[m][n][r]);
            }
        }
    }
}

// ---------------- aggregation (bf16 h) ----------------
// 4 waves/block, one node per wave; lane holds 4 consecutive features (8B ushort4).
template <bool RELU, bool OUTF32>
__global__ __launch_bounds__(256) void agg_kernel(const ushort_t* __restrict__ hb,
                                                  const float* __restrict__ dinv,
                                                  const float* __restrict__ bias,
                                                  const int* __restrict__ rowptr,
                                                  const int* __restrict__ ssort,
                                                  const float* __restrict__ wsort,
                                                  void* __restrict__ outp, int N, int E) {
    int node = blockIdx.x * 4 + (threadIdx.x >> 6);
    int lane = threadIdx.x & 63;
    if (node >= N) return;
    float di = dinv[node], d2 = di * di;
    ushort4 hv = *(const ushort4*)&hb[(size_t)node * 256 + lane * 4];
    float a0 = d2 * u2f(hv.x), a1 = d2 * u2f(hv.y), a2 = d2 * u2f(hv.z), a3 = d2 * u2f(hv.w);
    int s = rowptr[node];
    int e = (node == N - 1) ? E : rowptr[node + 1];
    for (int base = s; base < e; base += 64) {
        int m = e - base;
        if (m > 64) m = 64;
        int sl = 0;
        float wl = 0.f;
        if (lane < m) { sl = ssort[base + lane]; wl = wsort[base + lane]; }
#pragma unroll 4
        for (int j = 0; j < m; ++j) {
            int src = __shfl(sl, j);
            float w = __shfl(wl, j);
            ushort4 v = *(const ushort4*)&hb[(size_t)src * 256 + lane * 4];
            a0 = fmaf(w, u2f(v.x), a0);
            a1 = fmaf(w, u2f(v.y), a1);
            a2 = fmaf(w, u2f(v.z), a2);
            a3 = fmaf(w, u2f(v.w), a3);
        }
    }
    const float4 bb = *(const float4*)&bias[lane * 4];
    a0 += bb.x; a1 += bb.y; a2 += bb.z; a3 += bb.w;
    if (RELU) {
        a0 = fmaxf(a0, 0.f); a1 = fmaxf(a1, 0.f);
        a2 = fmaxf(a2, 0.f); a3 = fmaxf(a3, 0.f);
    }
    if (OUTF32) {
        *(float4*)((float*)outp + (size_t)node * 256 + lane * 4) = make_float4(a0, a1, a2, a3);
    } else {
        ushort4 o;
        o.x = f2b(a0); o.y = f2b(a1); o.z = f2b(a2); o.w = f2b(a3);
        *(ushort4*)((ushort_t*)outp + (size_t)node * 256 + lane * 4) = o;
    }
}

extern "C" void kernel_launch(void* const* d_in, const int* in_sizes, int n_in,
                              void* d_out, int out_size, void* d_ws, size_t ws_size,
                              hipStream_t stream) {
    const float* x  = (const float*)d_in[0];
    const int*   ei = (const int*)d_in[1];
    const float* ew = (const float*)d_in[2];
    const float* W1 = (const float*)d_in[3];
    const float* b1 = (const float*)d_in[4];
    const float* W2 = (const float*)d_in[5];
    const float* b2 = (const float*)d_in[6];
    const float* W3 = (const float*)d_in[7];
    const float* b3 = (const float*)d_in[8];
    const int N = in_sizes[0] / 512;
    const int E = in_sizes[2];
    const int* row = ei;
    const int* col = ei + E;
    float* out = (float*)d_out;

    const int MB = (N + 127) / 128;        // 782
    const size_t Npad = (size_t)MB * 128;  // 100096

    char* ws = (char*)d_ws;
    size_t off = 0;
    auto alloc = [&](size_t bytes) -> void* {
        void* p = ws + off;
        off += (bytes + 255) / 256 * 256;
        return p;
    };
    ushort_t* hb   = (ushort_t*)alloc(Npad * D * sizeof(ushort_t));  // 51.2 MB
    ushort_t* ab   = (ushort_t*)alloc(Npad * D * sizeof(ushort_t));  // 51.2 MB
    ushort_t* WT1  = (ushort_t*)alloc((size_t)512 * D * sizeof(ushort_t));
    ushort_t* WT2  = (ushort_t*)alloc((size_t)256 * D * sizeof(ushort_t));
    ushort_t* WT3  = (ushort_t*)alloc((size_t)256 * D * sizeof(ushort_t));
    float* dinv    = (float*)alloc((size_t)N * sizeof(float));
    int*   cnt     = (int*)alloc((size_t)N * sizeof(int));
    int*   fill    = (int*)alloc((size_t)N * sizeof(int));
    int*   rowptr  = (int*)alloc((size_t)(N + 1) * sizeof(int));
    int*   bsum    = (int*)alloc(4096 * sizeof(int));
    int*   ssort   = (int*)alloc((size_t)E * sizeof(int));
    float* wsort   = (float*)alloc((size_t)E * sizeof(float));

    hipMemsetAsync(dinv, 0, (size_t)N * sizeof(float), stream);
    hipMemsetAsync(cnt, 0, (size_t)N * sizeof(int), stream);
    hipMemsetAsync(fill, 0, (size_t)N * sizeof(int), stream);

    int gE = (E + 255) / 256;
    int gN = (N + 255) / 256;
    cvtT_kernel<<<(512 * D + 255) / 256, 256, 0, stream>>>(W1, WT1, 512, D);
    cvtT_kernel<<<(256 * D + 255) / 256, 256, 0, stream>>>(W2, WT2, 256, D);
    cvtT_kernel<<<(256 * D + 255) / 256, 256, 0, stream>>>(W3, WT3, 256, D);
    hist_kernel<<<gE, 256, 0, stream>>>(col, ew, dinv, cnt, E);
    dinv_kernel<<<gN, 256, 0, stream>>>(dinv, N);
    int nb = (N + SCAN_CHUNK - 1) / SCAN_CHUNK;
    scan1_kernel<<<nb, 256, 0, stream>>>(cnt, rowptr, bsum, N);
    scan2_kernel<<<1, 64, 0, stream>>>(bsum, nb);
    scan3_kernel<<<gN, 256, 0, stream>>>(rowptr, bsum, N);
    scatter_kernel<<<gE, 256, 0, stream>>>(row, col, ew, dinv, rowptr, fill, ssort, wsort, E);

    dim3 gg(2, MB);   // x = col-tile so both col-tiles of a row-pair are dispatch-adjacent
    int gA = (N + 3) / 4;
    // layer 1
    gemm_mfma<512, true><<<gg, 256, 0, stream>>>(x, WT1, hb, N);
    agg_kernel<true, false><<<gA, 256, 0, stream>>>(hb, dinv, b1, rowptr, ssort, wsort, ab, N, E);
    // layer 2
    gemm_mfma<256, false><<<gg, 256, 0, stream>>>(ab, WT2, hb, N);
    agg_kernel<true, false><<<gA, 256, 0, stream>>>(hb, dinv, b2, rowptr, ssort, wsort, ab, N, E);
    // layer 3
    gemm_mfma<256, false><<<gg, 256, 0, stream>>>(ab, WT3, hb, N);
    agg_kernel<false, true><<<gA, 256, 0, stream>>>(hb, dinv, b3, rowptr, ssort, wsort, out, N, E);
}

// Round 3
// 728.653 us; speedup vs baseline: 2.2920x; 1.1313x over previous
//
#include <hip/hip_runtime.h>
#include <hip/hip_bf16.h>

// GCN 3-layer. Round 3: packed 64-bit histogram atomic (cnt<<48 | fixed-point deg),
// int2 edge records {src, norm} to halve random-store transactions.
// bf16 MFMA GEMM + bf16 gather-aggregation unchanged from round 2.

#define D 256
#define SCAN_CHUNK 2048
#define FIXSCALE 1099511627776.0f          /* 2^40 (exact pow2 scale) */
#define FIXINV   9.094947017729282e-13     /* 2^-40 */

typedef unsigned short ushort_t;
typedef unsigned long long u64;
typedef float f32x4 __attribute__((ext_vector_type(4)));
typedef short bf16x8 __attribute__((ext_vector_type(8)));

__device__ __forceinline__ float u2f(ushort_t u) {
    return __uint_as_float(((unsigned)u) << 16);
}
__device__ __forceinline__ ushort_t f2b(float f) {   // round-to-nearest-even
    unsigned u = __float_as_uint(f);
    return (ushort_t)((u + 0x7FFFu + ((u >> 16) & 1u)) >> 16);
}
__device__ __forceinline__ void gload_lds16(const ushort_t* g, ushort_t* l) {
    __builtin_amdgcn_global_load_lds((const __attribute__((address_space(1))) unsigned int*)g,
                                     (__attribute__((address_space(3))) unsigned int*)l, 16, 0, 0);
}

// ---------------- CSR build ----------------
// one packed atomic per edge: bits[63:48]=count, bits[47:0]=sum(ew)*2^40 (exact)
__global__ __launch_bounds__(256) void hist_kernel(const int* __restrict__ col,
                                                   const float* __restrict__ ew,
                                                   u64* __restrict__ pk, int E) {
    int e = blockIdx.x * 256 + threadIdx.x;
    if (e < E) {
        u64 t = (1ull << 48) + (u64)(ew[e] * FIXSCALE);
        atomicAdd(&pk[col[e]], t);
    }
}

__global__ __launch_bounds__(256) void dinv_kernel(const u64* __restrict__ pk,
                                                   float* __restrict__ dinv, int N) {
    int i = blockIdx.x * 256 + threadIdx.x;
    if (i < N) {
        u64 p = pk[i];
        float deg = (float)((double)(p & 0xFFFFFFFFFFFFull) * FIXINV) + 1.0f;
        dinv[i] = rsqrtf(deg);
    }
}

// exclusive scan of counts (pk>>48) -> rowptr; per-chunk totals -> bsum
__global__ __launch_bounds__(256) void scan1_kernel(const u64* __restrict__ pk,
                                                    int* __restrict__ rowptr,
                                                    int* __restrict__ bsum, int N) {
    __shared__ int sd[256];
    int b = blockIdx.x, t = threadIdx.x;
    int base = b * SCAN_CHUNK + t * 8;
    int v[8];
    int tsum = 0;
#pragma unroll
    for (int j = 0; j < 8; j++) {
        v[j] = (base + j < N) ? (int)(pk[base + j] >> 48) : 0;
        tsum += v[j];
    }
    sd[t] = tsum;
    __syncthreads();
#pragma unroll
    for (int off = 1; off < 256; off <<= 1) {
        int x = (t >= off) ? sd[t - off] : 0;
        __syncthreads();
        sd[t] += x;
        __syncthreads();
    }
    int excl = sd[t] - tsum;
    if (t == 255) bsum[b] = sd[255];
    int run = excl;
#pragma unroll
    for (int j = 0; j < 8; j++) {
        if (base + j < N) rowptr[base + j] = run;
        run += v[j];
    }
}

__global__ void scan2_kernel(int* __restrict__ bsum, int nb) {
    int lane = threadIdx.x;
    int running = 0;
    for (int base = 0; base < nb; base += 64) {
        int idx = base + lane;
        int v = (idx < nb) ? bsum[idx] : 0;
        int orig = v;
#pragma unroll
        for (int off = 1; off < 64; off <<= 1) {
            int x = __shfl_up(v, off);
            if (lane >= off) v += x;
        }
        if (idx < nb) bsum[idx] = v - orig + running;
        running += __shfl(v, 63);
    }
}

__global__ __launch_bounds__(256) void scan3_kernel(int* __restrict__ rowptr,
                                                    const int* __restrict__ bsum, int N) {
    int i = blockIdx.x * 256 + threadIdx.x;
    if (i < N) rowptr[i] += bsum[i / SCAN_CHUNK];
}

// one 8B record {src, norm} per edge (single aligned store + one 4B atomic)
__global__ __launch_bounds__(256) void scatter_kernel(const int* __restrict__ row,
                                                      const int* __restrict__ col,
                                                      const float* __restrict__ ew,
                                                      const float* __restrict__ dinv,
                                                      const int* __restrict__ rowptr,
                                                      int* __restrict__ fill,
                                                      int2* __restrict__ rec, int E) {
    int e = blockIdx.x * 256 + threadIdx.x;
    if (e < E) {
        int c = col[e], r = row[e];
        float nrm = dinv[r] * ew[e] * dinv[c];
        int pos = rowptr[c] + atomicAdd(&fill[c], 1);
        rec[pos] = make_int2(r, __float_as_int(nrm));
    }
}

// W[K][C] fp32 -> WT[C][K] bf16
__global__ __launch_bounds__(256) void cvtT_kernel(const float* __restrict__ W,
                                                   ushort_t* __restrict__ WT, int K, int C) {
    int i = blockIdx.x * 256 + threadIdx.x;
    if (i < K * C) {
        int c = i / K, k = i - c * K;
        WT[i] = f2b(W[(size_t)k * C + c]);
    }
}

// ---------------- MFMA GEMM ----------------
template <int K, bool AF32>
__global__ __launch_bounds__(256) void gemm_mfma(const void* __restrict__ Ap,
                                                 const ushort_t* __restrict__ WT,
                                                 ushort_t* __restrict__ C, int nvalid) {
    __shared__ ushort_t As[128 * 64];
    __shared__ ushort_t Bs[128 * 64];
    const int tid = threadIdx.x;
    const int lane = tid & 63, wave = tid >> 6;
    const int wrow = wave >> 1, wcol = wave & 1;
    const int fr = lane & 15, fq = lane >> 4;
    const int c0 = blockIdx.x * 128;
    const int r0 = blockIdx.y * 128;

    f32x4 acc[4][4] = {};

    for (int k0 = 0; k0 < K; k0 += 64) {
        if constexpr (AF32) {
            const float* Af = (const float*)Ap;
#pragma unroll
            for (int i = 0; i < 8; ++i) {
                int idx = i * 256 + tid;
                int rowt = idx >> 4;
                int c4 = idx & 15;
                int grow = r0 + rowt;
                if (grow >= nvalid) grow = nvalid - 1;
                float4 v = *(const float4*)&Af[(size_t)grow * K + k0 + c4 * 4];
                ushort4 h;
                h.x = f2b(v.x); h.y = f2b(v.y); h.z = f2b(v.z); h.w = f2b(v.w);
                int slot = c4 >> 1, half = c4 & 1;
                int off = rowt * 64 + ((slot ^ (rowt & 7)) << 3) + (half << 2);
                *(ushort4*)&As[off] = h;
            }
        } else {
            const ushort_t* Ab = (const ushort_t*)Ap;
#pragma unroll
            for (int q = 0; q < 4; ++q) {
                int qa = wave * 4 + q;
                int rowt = qa * 8 + (lane >> 3);
                int g = (lane & 7) ^ (lane >> 3);
                gload_lds16(&Ab[(size_t)(r0 + rowt) * K + k0 + g * 8], &As[qa * 512]);
            }
        }
#pragma unroll
        for (int q = 0; q < 4; ++q) {
            int qb = wave * 4 + q;
            int rowt = qb * 8 + (lane >> 3);
            int g = (lane & 7) ^ (lane >> 3);
            gload_lds16(&WT[(size_t)(c0 + rowt) * K + k0 + g * 8], &Bs[qb * 512]);
        }
        __syncthreads();

        bf16x8 aF[2][4], bF[2][4];
#pragma unroll
        for (int kk = 0; kk < 2; ++kk) {
            int g = (kk * 4 + fq) ^ (fr & 7);
#pragma unroll
            for (int m = 0; m < 4; ++m) {
                int arow = wrow * 64 + m * 16 + fr;
                aF[kk][m] = *(const bf16x8*)&As[arow * 64 + g * 8];
            }
#pragma unroll
            for (int n = 0; n < 4; ++n) {
                int bcol = wcol * 64 + n * 16 + fr;
                bF[kk][n] = *(const bf16x8*)&Bs[bcol * 64 + g * 8];
            }
        }
#pragma unroll
        for (int kk = 0; kk < 2; ++kk)
#pragma unroll
            for (int m = 0; m < 4; ++m)
#pragma unroll
                for (int n = 0; n < 4; ++n)
                    acc[m][n] = __builtin_amdgcn_mfma_f32_16x16x32_bf16(
                        aF[kk][m], bF[kk][n], acc[m][n], 0, 0, 0);
        __syncthreads();
    }

#pragma unroll
    for (int m = 0; m < 4; ++m) {
        int gr0 = r0 + wrow * 64 + m * 16 + fq * 4;
#pragma unroll
        for (int n = 0; n < 4; ++n) {
            int gc = c0 + wcol * 64 + n * 16 + fr;
#pragma unroll
            for (int r = 0; r < 4; ++r) {
                int gr = gr0 + r;
                if (gr < nvalid) C[(size_t)gr * D + gc] = f2b(acc[m][n][r]);
            }
        }
    }
}

// ---------------- aggregation (bf16 h, int2 edge records) ----------------
template <bool RELU, bool OUTF32>
__global__ __launch_bounds__(256) void agg_kernel(const ushort_t* __restrict__ hb,
                                                  const float* __restrict__ dinv,
                                                  const float* __restrict__ bias,
                                                  const int* __restrict__ rowptr,
                                                  const int2* __restrict__ rec,
                                                  void* __restrict__ outp, int N, int E) {
    int node = blockIdx.x * 4 + (threadIdx.x >> 6);
    int lane = threadIdx.x & 63;
    if (node >= N) return;
    float di = dinv[node], d2 = di * di;
    ushort4 hv = *(const ushort4*)&hb[(size_t)node * 256 + lane * 4];
    float a0 = d2 * u2f(hv.x), a1 = d2 * u2f(hv.y), a2 = d2 * u2f(hv.z), a3 = d2 * u2f(hv.w);
    int s = rowptr[node];
    int e = (node == N - 1) ? E : rowptr[node + 1];
    for (int base = s; base < e; base += 64) {
        int m = e - base;
        if (m > 64) m = 64;
        int2 rl = make_int2(0, 0);
        if (lane < m) rl = rec[base + lane];
#pragma unroll 4
        for (int j = 0; j < m; ++j) {
            int src = __shfl(rl.x, j);
            float w = __uint_as_float(__shfl(rl.y, j));
            ushort4 v = *(const ushort4*)&hb[(size_t)src * 256 + lane * 4];
            a0 = fmaf(w, u2f(v.x), a0);
            a1 = fmaf(w, u2f(v.y), a1);
            a2 = fmaf(w, u2f(v.z), a2);
            a3 = fmaf(w, u2f(v.w), a3);
        }
    }
    const float4 bb = *(const float4*)&bias[lane * 4];
    a0 += bb.x; a1 += bb.y; a2 += bb.z; a3 += bb.w;
    if (RELU) {
        a0 = fmaxf(a0, 0.f); a1 = fmaxf(a1, 0.f);
        a2 = fmaxf(a2, 0.f); a3 = fmaxf(a3, 0.f);
    }
    if (OUTF32) {
        *(float4*)((float*)outp + (size_t)node * 256 + lane * 4) = make_float4(a0, a1, a2, a3);
    } else {
        ushort4 o;
        o.x = f2b(a0); o.y = f2b(a1); o.z = f2b(a2); o.w = f2b(a3);
        *(ushort4*)((ushort_t*)outp + (size_t)node * 256 + lane * 4) = o;
    }
}

extern "C" void kernel_launch(void* const* d_in, const int* in_sizes, int n_in,
                              void* d_out, int out_size, void* d_ws, size_t ws_size,
                              hipStream_t stream) {
    const float* x  = (const float*)d_in[0];
    const int*   ei = (const int*)d_in[1];
    const float* ew = (const float*)d_in[2];
    const float* W1 = (const float*)d_in[3];
    const float* b1 = (const float*)d_in[4];
    const float* W2 = (const float*)d_in[5];
    const float* b2 = (const float*)d_in[6];
    const float* W3 = (const float*)d_in[7];
    const float* b3 = (const float*)d_in[8];
    const int N = in_sizes[0] / 512;
    const int E = in_sizes[2];
    const int* row = ei;
    const int* col = ei + E;
    float* out = (float*)d_out;

    const int MB = (N + 127) / 128;
    const size_t Npad = (size_t)MB * 128;

    char* ws = (char*)d_ws;
    size_t off = 0;
    auto alloc = [&](size_t bytes) -> void* {
        void* p = ws + off;
        off += (bytes + 255) / 256 * 256;
        return p;
    };
    ushort_t* hb   = (ushort_t*)alloc(Npad * D * sizeof(ushort_t));  // 51.2 MB
    ushort_t* ab   = (ushort_t*)alloc(Npad * D * sizeof(ushort_t));  // 51.2 MB
    ushort_t* WT1  = (ushort_t*)alloc((size_t)512 * D * sizeof(ushort_t));
    ushort_t* WT2  = (ushort_t*)alloc((size_t)256 * D * sizeof(ushort_t));
    ushort_t* WT3  = (ushort_t*)alloc((size_t)256 * D * sizeof(ushort_t));
    u64*   pk      = (u64*)alloc((size_t)N * sizeof(u64));
    float* dinv    = (float*)alloc((size_t)N * sizeof(float));
    int*   fill    = (int*)alloc((size_t)N * sizeof(int));
    int*   rowptr  = (int*)alloc((size_t)(N + 1) * sizeof(int));
    int*   bsum    = (int*)alloc(4096 * sizeof(int));
    int2*  rec     = (int2*)alloc((size_t)E * sizeof(int2));

    hipMemsetAsync(pk, 0, (size_t)N * sizeof(u64), stream);
    hipMemsetAsync(fill, 0, (size_t)N * sizeof(int), stream);

    int gE = (E + 255) / 256;
    int gN = (N + 255) / 256;
    cvtT_kernel<<<(512 * D + 255) / 256, 256, 0, stream>>>(W1, WT1, 512, D);
    cvtT_kernel<<<(256 * D + 255) / 256, 256, 0, stream>>>(W2, WT2, 256, D);
    cvtT_kernel<<<(256 * D + 255) / 256, 256, 0, stream>>>(W3, WT3, 256, D);
    hist_kernel<<<gE, 256, 0, stream>>>(col, ew, pk, E);
    dinv_kernel<<<gN, 256, 0, stream>>>(pk, dinv, N);
    int nb = (N + SCAN_CHUNK - 1) / SCAN_CHUNK;
    scan1_kernel<<<nb, 256, 0, stream>>>(pk, rowptr, bsum, N);
    scan2_kernel<<<1, 64, 0, stream>>>(bsum, nb);
    scan3_kernel<<<gN, 256, 0, stream>>>(rowptr, bsum, N);
    scatter_kernel<<<gE, 256, 0, stream>>>(row, col, ew, dinv, rowptr, fill, rec, E);

    dim3 gg(2, MB);
    int gA = (N + 3) / 4;
    // layer 1
    gemm_mfma<512, true><<<gg, 256, 0, stream>>>(x, WT1, hb, N);
    agg_kernel<true, false><<<gA, 256, 0, stream>>>(hb, dinv, b1, rowptr, rec, ab, N, E);
    // layer 2
    gemm_mfma<256, false><<<gg, 256, 0, stream>>>(ab, WT2, hb, N);
    agg_kernel<true, false><<<gA, 256, 0, stream>>>(hb, dinv, b2, rowptr, rec, ab, N, E);
    // layer 3
    gemm_mfma<256, false><<<gg, 256, 0, stream>>>(ab, WT3, hb, N);
    agg_kernel<false, true><<<gA, 256, 0, stream>>>(hb, dinv, b3, rowptr, rec, out, N, E);
}